// Round 11
// baseline (357.979 us; speedup 1.0000x reference)
//
#include <hip/hip_runtime.h>
#include <hip/hip_bf16.h>

#define H  1024
#define S  32768
#define H2 2048
#define H3 3072

typedef __attribute__((ext_vector_type(8))) short bf16x8;   // 8 bf16 = 4 VGPRs
typedef __attribute__((ext_vector_type(4))) float f32x4;    // MFMA C/D frag

// ---------- fp32 -> bf16 (RNE) helpers ----------
__device__ __forceinline__ unsigned short f2bf(float f) {
    unsigned u = __float_as_uint(f);
    u += 0x7fffu + ((u >> 16) & 1u);
    return (unsigned short)(u >> 16);
}

__device__ __forceinline__ unsigned cvt_pk(float lo, float hi) {
    __hip_bfloat162 h = __float22bfloat162_rn(make_float2(lo, hi));
    unsigned u;
    __builtin_memcpy(&u, &h, 4);
    return u;
}

// fast tanh via v_exp_f32: tanh(x) = 1 - 2/(e^(2x)+1)
__device__ __forceinline__ float tanh_fast(float x) {
    float e = __expf(2.0f * x);
    return 1.0f - 2.0f / (e + 1.0f);
}

// ---------- async global->LDS 16B ----------
__device__ __forceinline__ void async_copy16(const void* g, void* l) {
    __builtin_amdgcn_global_load_lds(
        (const __attribute__((address_space(1))) unsigned int*)g,
        (__attribute__((address_space(3))) unsigned int*)l,
        16, 0, 0);
}

// ---------- fused prep (PROVEN function, verbatim; do_enc=0) ----------
__global__ void prep_all(const float* __restrict__ enc, const float* __restrict__ attn_w,
                         const float* __restrict__ attn_b, const float* __restrict__ hidden,
                         unsigned short* __restrict__ ebf, unsigned short* __restrict__ w2b,
                         float* __restrict__ dvec, float* __restrict__ logits, int do_enc) {
    int b = blockIdx.x;
    if (b < 32) {
        // zero the logits (gemm accumulates via atomicAdd)
        ((float4*)logits)[b * 256 + threadIdx.x] = (float4){0.f, 0.f, 0.f, 0.f};
        return;
    }
    b -= 32;
    if (do_enc) {
        if (b < 32768) {
            size_t idx4 = (size_t)b * 256 + threadIdx.x;       // float4 chunk id
            float4 f = ((const float4*)enc)[idx4];
            ushort4 u;
            u.x = f2bf(f.x); u.y = f2bf(f.y); u.z = f2bf(f.z); u.w = f2bf(f.w);
            ((ushort4*)ebf)[idx4] = u;
            return;
        }
        b -= 32768;
    }
    if (b < 1024) {
        // W2 = attn_w[:, 2048:3072] -> bf16 row-major (N=1024 x K=1024)
        int idx4 = b * 256 + threadIdx.x;
        int n = idx4 >> 8;
        int c = (idx4 & 255) * 4;
        float4 f = *(const float4*)(attn_w + (size_t)n * H3 + H2 + c);
        ushort4 u;
        u.x = f2bf(f.x); u.y = f2bf(f.y); u.z = f2bf(f.z); u.w = f2bf(f.w);
        *(ushort4*)(w2b + (size_t)n * H + c) = u;
        return;
    }
    // dvec[i] = attn_b[i] + sum_{k<2048} hidden[k]*attn_w[i][k]
    b -= 1024;
    int wv = threadIdx.x >> 6, lane = threadIdx.x & 63;
    int row = b * 4 + wv;
    const float* wrow = attn_w + (size_t)row * H3;
    float s = 0.f;
    #pragma unroll
    for (int j = 0; j < 32; ++j) {
        int k = lane + j * 64;
        s += wrow[k] * hidden[k];
    }
    #pragma unroll
    for (int m = 1; m <= 32; m <<= 1) s += __shfl_xor(s, m);
    if (lane == 0) dvec[row] = s + attn_b[row];
}

// ---------- fused gemm v4: 2-phase double-buffer, BK=32, k-major LDS ----------
// ROUND-10 POST-MORTEM: staging throughput is ~4 MB/us PER RESIDENT BLOCK
// (r0: 3 blk -> 11.6 MB/us; r9: 2.2 -> 8.9; r10: 2.0 -> 8.1), far below any
// fabric limit (HBM 8.7%) -> the per-block stage->drain->compute serialization
// is the bottleneck. Fix: in-block 2-phase pipeline (guide T3 minimum recipe):
//   STAGE(buf^1, kt+1); COMPUTE(buf, kt); __syncthreads(); flip.
// The barrier's compiler-inserted vmcnt(0) now drains loads whose latency was
// hidden under COMPUTE. Distinct __shared__ arrays per buffer so alias
// analysis cannot insert a spurious early vmcnt before the ds_reads.
// Safety: write buf^1 in iter kt; last READ of buf^1 was in iter kt-1, and the
// barrier at end of kt-1 (waits lgkmcnt(0) per wave) orders read-before-write.
//
// BK=32 + K-MAJOR LDS layout (free transpose via per-lane gload_lds source):
//   chunk (row r, kchunk j) stored at LDS chunk j*ROWS + r.
//   Consumer reads are stride-16B contiguous per 16-lane group -> conflict-free
//   with NO XOR swizzle. LDS = 2*(16KB A + 16KB B) = 64 KB -> 2 blocks/CU kept.
// Tile BM=128 x BN=256, grid decode, epilogue: unchanged from verified r10.
__global__ __launch_bounds__(256, 2) void attn_gemm_db(
        const float* __restrict__ enc, const unsigned short* __restrict__ w2b,
        const float* __restrict__ dvec, const float* __restrict__ vw,
        float* __restrict__ logits) {
    __shared__ float Af0[128 * 32];              // 16 KB fp32 A (k-major)
    __shared__ float Af1[128 * 32];              // 16 KB
    __shared__ unsigned short Bt0[256 * 32];     // 16 KB bf16 B (k-major)
    __shared__ unsigned short Bt1[256 * 32];     // 16 KB

    const int tid = threadIdx.x;
    const int b = blockIdx.x;
    const int rowBlock = (b & 7) * 32 + (b >> 5);   // 0..255 (bijective)
    const int colBlock = (b >> 3) & 3;              // 0..3

    const int lane = tid & 63;
    const int wv = tid >> 6;
    const int waveM = wv >> 1, waveN = wv & 1;      // wave tile: 64 rows x 128 cols
    const int quad = lane >> 4, l16 = lane & 15;

    f32x4 acc[4][8];
    #pragma unroll
    for (int mi = 0; mi < 4; ++mi)
        #pragma unroll
        for (int ni = 0; ni < 8; ++ni)
            acc[mi][ni] = (f32x4){0.f, 0.f, 0.f, 0.f};

    const size_t aRow0 = (size_t)(rowBlock * 128) * H;   // fp32 elements
    const size_t bRow0 = (size_t)(colBlock * 256) * H;   // bf16 elements

    // STAGE: 1024 A-chunks (jA=c>>7, rA=c&127) + 1024 B-chunks (jB=c>>8, rB=c&255)
    // dest is linear (chunk c at byte c*16 -> wave-uniform base + lane*16).
    auto STAGE = [&](float* Ab, unsigned short* Bb, int k0) {
        #pragma unroll
        for (int p = 0; p < 4; ++p) {
            int c = p * 256 + tid;
            async_copy16(enc + aRow0 + (size_t)(c & 127) * H + k0 + ((c >> 7) << 2),
                         (char*)Ab + (size_t)c * 16);
        }
        #pragma unroll
        for (int p = 0; p < 4; ++p) {
            int c = p * 256 + tid;
            async_copy16(w2b + bRow0 + (size_t)(c & 255) * H + k0 + ((c >> 8) << 3),
                         (char*)Bb + (size_t)c * 16);
        }
    };

    // COMPUTE one BK=32 tile: A frag = k-chunks {2q,2q+1}; B frag = k-chunk q.
    auto COMPUTE = [&](const float* Ab, const unsigned short* Bb) {
        bf16x8 af[4], bfr[8];
        #pragma unroll
        for (int i = 0; i < 4; ++i) {
            int ar = waveM * 64 + i * 16 + l16;
            float4 f0 = *(const float4*)(Ab + ((2 * quad) * 128 + ar) * 4);
            float4 f1 = *(const float4*)(Ab + ((2 * quad + 1) * 128 + ar) * 4);
            uint4 u;
            u.x = cvt_pk(f0.x, f0.y);
            u.y = cvt_pk(f0.z, f0.w);
            u.z = cvt_pk(f1.x, f1.y);
            u.w = cvt_pk(f1.z, f1.w);
            __builtin_memcpy(&af[i], &u, 16);
        }
        #pragma unroll
        for (int j = 0; j < 8; ++j) {
            int br = waveN * 128 + j * 16 + l16;
            bfr[j] = *(const bf16x8*)((const char*)Bb + ((size_t)quad * 256 + br) * 16);
        }
        #pragma unroll
        for (int mi = 0; mi < 4; ++mi)
            #pragma unroll
            for (int ni = 0; ni < 8; ++ni)
                acc[mi][ni] = __builtin_amdgcn_mfma_f32_16x16x32_bf16(
                    af[mi], bfr[ni], acc[mi][ni], 0, 0, 0);
    };

    // ---- 2-phase pipeline over 32 BK=32 tiles ----
    STAGE(Af0, Bt0, 0);
    __syncthreads();                       // drain prologue stage
    #pragma unroll 1
    for (int t = 0; t < 15; ++t) {
        STAGE(Af1, Bt1, (2 * t + 1) * 32); // issue next tile's loads
        COMPUTE(Af0, Bt0);                 // compute current (hides load latency)
        __syncthreads();                   // drain Af1/Bt1 loads; all reads of Af0 done
        STAGE(Af0, Bt0, (2 * t + 2) * 32);
        COMPUTE(Af1, Bt1);
        __syncthreads();
    }
    STAGE(Af1, Bt1, 31 * 32);              // last tile
    COMPUTE(Af0, Bt0);                     // kt = 30
    __syncthreads();
    COMPUTE(Af1, Bt1);                     // kt = 31 (no trailing barrier needed)

    // ---------- epilogue: tanh + v_w-dot + shuffle-reduce + atomic ----------
    float rowsum[4][4];
    #pragma unroll
    for (int mi = 0; mi < 4; ++mi)
        #pragma unroll
        for (int r = 0; r < 4; ++r) rowsum[mi][r] = 0.f;

    #pragma unroll
    for (int ni = 0; ni < 8; ++ni) {
        int colg = colBlock * 256 + waveN * 128 + ni * 16 + l16;
        float dv = dvec[colg];
        float vv = vw[colg];
        #pragma unroll
        for (int mi = 0; mi < 4; ++mi)
            #pragma unroll
            for (int r = 0; r < 4; ++r)
                rowsum[mi][r] += tanh_fast(acc[mi][ni][r] + dv) * vv;
    }

    #pragma unroll
    for (int mi = 0; mi < 4; ++mi)
        #pragma unroll
        for (int r = 0; r < 4; ++r) {
            float s = rowsum[mi][r];
            s += __shfl_xor(s, 1);
            s += __shfl_xor(s, 2);
            s += __shfl_xor(s, 4);
            s += __shfl_xor(s, 8);
            rowsum[mi][r] = s;
        }

    if (l16 == 0) {
        int rbase = rowBlock * 128 + waveM * 64 + quad * 4;
        #pragma unroll
        for (int mi = 0; mi < 4; ++mi)
            #pragma unroll
            for (int r = 0; r < 4; ++r)
                atomicAdd(&logits[rbase + mi * 16 + r], rowsum[mi][r]);
    }
}

// ---------- softmax over 32768 logits, single workgroup, in-place ----------
__global__ __launch_bounds__(1024) void softmax_k(float* __restrict__ x) {
    __shared__ float red[16];
    const int tid = threadIdx.x;
    const int lane = tid & 63, wv = tid >> 6;

    float v[32];
    float m = -1e30f;
    #pragma unroll
    for (int i = 0; i < 32; ++i) {
        v[i] = x[tid + (i << 10)];
        m = fmaxf(m, v[i]);
    }
    #pragma unroll
    for (int o = 1; o < 64; o <<= 1) m = fmaxf(m, __shfl_xor(m, o));
    if (lane == 0) red[wv] = m;
    __syncthreads();
    #pragma unroll
    for (int i = 0; i < 16; ++i) m = fmaxf(m, red[i]);
    __syncthreads();

    float s = 0.f;
    #pragma unroll
    for (int i = 0; i < 32; ++i) {
        v[i] = expf(v[i] - m);
        s += v[i];
    }
    #pragma unroll
    for (int o = 1; o < 64; o <<= 1) s += __shfl_xor(s, o);
    if (lane == 0) red[wv] = s;
    __syncthreads();
    float tot = 0.f;
    #pragma unroll
    for (int i = 0; i < 16; ++i) tot += red[i];
    float inv = 1.0f / tot;

    #pragma unroll
    for (int i = 0; i < 32; ++i) x[tid + (i << 10)] = v[i] * inv;
}

extern "C" void kernel_launch(void* const* d_in, const int* in_sizes, int n_in,
                              void* d_out, int out_size, void* d_ws, size_t ws_size,
                              hipStream_t stream) {
    const float* hidden = (const float*)d_in[0];   // (1, 2048)
    const float* enc    = (const float*)d_in[1];   // (32768, 1024)
    const float* attn_w = (const float*)d_in[2];   // (1024, 3072)
    const float* attn_b = (const float*)d_in[3];   // (1024,)
    const float* v_w    = (const float*)d_in[4];   // (1, 1024)
    float* out = (float*)d_out;                    // (32768,) fp32

    const size_t W2_BYTES = (size_t)H * H * 2;     // 2 MB
    unsigned short* w2b = (unsigned short*)d_ws;
    float* dvec = (float*)((char*)d_ws + W2_BYTES);

    // prep (proven function, do_enc=0): zero logits + W2->bf16 + dvec
    prep_all<<<dim3(32 + 1024 + 256), dim3(256), 0, stream>>>(
        enc, attn_w, attn_b, hidden, nullptr, w2b, dvec, out, 0);
    attn_gemm_db<<<dim3(1024), dim3(256), 0, stream>>>(enc, w2b, dvec, v_w, out);
    softmax_k<<<dim3(1), dim3(1024), 0, stream>>>(out);
}